// Round 14
// baseline (31.972 us; speedup 1.0000x reference)
//
#include <hip/hip_runtime.h>
#include <hip/hip_bf16.h>

// DecoderBlock: block-sparse masked linear (8 GEMMs M=256,N=1024,K=1024)
// + BatchNorm1d (batch stats; bias cancels exactly) + Swish.
// Round-14: ONE dispatch, zero workspace. Block = full batch x 32 features
// (BN stats block-local). grid 256 = 8g x 32nt; g=bid&7 -> XCD-local x slice.
// A: f32 global -> regs (issued BEFORE compute, latency hidden) -> bf16 via
//    v_perm pack -> swizzled ds_write into [256][64] bf16 LDS x2 (r10 layout).
// W: f32 reg-ring depth 4 issued 3 ahead -> bf16 -> swizzled ds_write (r10).
// No GLL, no conv kernel, no d_ws, 1 barrier/step, no mid-loop vmcnt drains
// (the only vm waits are compiler register-dependency waits on areg/breg).

typedef float  f32x4  __attribute__((ext_vector_type(4)));
typedef short  short8 __attribute__((ext_vector_type(8)));
typedef unsigned int u32x2 __attribute__((ext_vector_type(2)));
typedef unsigned int u32x4 __attribute__((ext_vector_type(4)));

// pack two f32 -> two bf16 (round-half-up: +0x8000 then take high16).
// v_perm_b32 selects bytes {u1.b3,u1.b2,u0.b3,u0.b2} -> (u0hi)|(u1hi<<16).
static __device__ __forceinline__ unsigned int pkbf(float a, float b) {
    const unsigned int u0 = __float_as_uint(a) + 0x8000u;
    const unsigned int u1 = __float_as_uint(b) + 0x8000u;
    return __builtin_amdgcn_perm(u1, u0, 0x07060302u);
}

__global__ __launch_bounds__(256, 1) void fused_kernel(
    const float* __restrict__ x, const float* __restrict__ W,
    const float* __restrict__ gamma, const float* __restrict__ beta,
    float* __restrict__ out)
{
    __shared__ __align__(16) char ldsA[2][32768];   // [256 r][64 k] bf16, swizzled
    __shared__ __align__(16) char ldsB[2][4096];    // [32 n][64 k] bf16, swizzled
    __shared__ float wps1[4][32], wps2[4][32];
    __shared__ float sa[32], sb[32];

    const int bid = blockIdx.x;
    const int g   = bid & 7;               // channel group -> XCD (round-robin)
    const int nt  = bid >> 3;              // 0..31
    const int o   = g * 4 + (nt >> 3);
    const int f0  = (nt & 7) * 32;
    const int gcol0 = o * 256 + f0;

    const int t    = threadIdx.x;
    const int wave = t >> 6;
    const int lane = t & 63;
    const int lr   = lane & 15;
    const int kq   = lane >> 4;

    f32x4 acc[4][2];
    const f32x4 zero = {0.f, 0.f, 0.f, 0.f};
#pragma unroll
    for (int i = 0; i < 4; ++i) { acc[i][0] = zero; acc[i][1] = zero; }

    f32x4 areg[16];                        // A stage: 64 f32/thread (one BK step)
    f32x4 breg[4][2];                      // W ring depth 4

    auto A_LOAD = [&](int st) {            // 16 coalesced f32x4 (16 lanes span 256B row-window)
        const float* asrc = x + g * 1024 + st * 64;
#pragma unroll
        for (int i = 0; i < 16; ++i) {
            const int cid = i * 256 + t;            // 0..4095
            const int r = cid >> 4, c = cid & 15;   // row 0..255, 16B chunk 0..15
            areg[i] = *(const f32x4*)(asrc + (size_t)r * 8192 + c * 4);
        }
    };
    auto A_WRITE = [&](int st) {           // cvt(perm) + swizzled ds_write_b64
        char* Ab = ldsA[st & 1];
#pragma unroll
        for (int i = 0; i < 16; ++i) {
            const int cid = i * 256 + t;
            const int r = cid >> 4, c = cid & 15;
            u32x2 d;
            d[0] = pkbf(areg[i][0], areg[i][1]);
            d[1] = pkbf(areg[i][2], areg[i][3]);
            const int ch = c >> 1, half = c & 1;    // bf16 16B-chunk, 8B half
            *(u32x2*)(Ab + r * 128 + ((ch ^ (r & 7)) * 16) + half * 8) = d;
        }
    };
    auto ISSUE_W = [&](int st) {           // 2 x 16B into ring slot st&3
        const int cp = st >> 2, kc = (st & 3) * 64;
        const float* bsrc = W + ((size_t)((o * 32 + g * 4 + cp) * 256 + f0)) * 256 + kc
                              + (size_t)(t >> 3) * 256 + (t & 7) * 8;
        breg[st & 3][0] = *(const f32x4*)bsrc;
        breg[st & 3][1] = *(const f32x4*)(bsrc + 4);
    };
    auto WRITEB = [&](int st) {            // cvt + one swizzled ds_write_b128
        const int n = t >> 3, c = t & 7;
        u32x4 d;
        d[0] = pkbf(breg[st & 3][0][0], breg[st & 3][0][1]);
        d[1] = pkbf(breg[st & 3][0][2], breg[st & 3][0][3]);
        d[2] = pkbf(breg[st & 3][1][0], breg[st & 3][1][1]);
        d[3] = pkbf(breg[st & 3][1][2], breg[st & 3][1][3]);
        *(u32x4*)(ldsB[st & 1] + n * 128 + ((c ^ (n & 7)) * 16)) = d;
    };
    auto COMPUTE = [&](int st) {
        const char* Ab = ldsA[st & 1];
        const char* Bb = ldsB[st & 1];
#pragma unroll
        for (int ks = 0; ks < 2; ++ks) {
            short8 af[4], bfr[2];
#pragma unroll
            for (int i = 0; i < 4; ++i) {
                const int ra = wave * 64 + i * 16 + lr;
                af[i] = *(const short8*)(Ab + ra * 128 + (((ks * 4 + kq) ^ (ra & 7)) * 16));
            }
#pragma unroll
            for (int j = 0; j < 2; ++j) {
                const int n = j * 16 + lr;
                bfr[j] = *(const short8*)(Bb + n * 128 + (((ks * 4 + kq) ^ (n & 7)) * 16));
            }
#pragma unroll
            for (int i = 0; i < 4; ++i)
#pragma unroll
                for (int j = 0; j < 2; ++j)
                    acc[i][j] = __builtin_amdgcn_mfma_f32_16x16x32_bf16(af[i], bfr[j], acc[i][j], 0, 0, 0);
        }
    };

    // prologue: A(0) loads, W(0..2); A_WRITE waits areg (W1,W2 stay in flight),
    // WRITEB(0) waits W(0).
    A_LOAD(0);
    ISSUE_W(0);
    ISSUE_W(1);
    ISSUE_W(2);
    A_WRITE(0);
    WRITEB(0);
    asm volatile("s_waitcnt lgkmcnt(0)" ::: "memory");
    __builtin_amdgcn_s_barrier();

#pragma unroll
    for (int st = 0; st < 16; ++st) {
        if (st < 15)  A_LOAD(st + 1);                  // issue EARLY: hidden by COMPUTE
        if (st <= 12) ISSUE_W(st + 3);                 // newest vm ops: W ring
        COMPUTE(st);                                   // reads parity st
        if (st < 15) {
            A_WRITE(st + 1);                           // waits areg only; parity st+1
            WRITEB(st + 1);                            // W(st+1) retired long ago
            asm volatile("s_waitcnt lgkmcnt(0)" ::: "memory");
            __builtin_amdgcn_s_barrier();
        }
    }

    // ---------------- fused BN + Swish epilogue ----------------
    float s1[2] = {0.f, 0.f}, s2[2] = {0.f, 0.f};
#pragma unroll
    for (int i = 0; i < 4; ++i)
#pragma unroll
        for (int j = 0; j < 2; ++j)
#pragma unroll
            for (int r = 0; r < 4; ++r) {
                const float v = acc[i][j][r];
                s1[j] += v; s2[j] += v * v;
            }
#pragma unroll
    for (int j = 0; j < 2; ++j) {          // reduce across kq groups (lanes sharing lr)
        s1[j] += __shfl_xor(s1[j], 16); s2[j] += __shfl_xor(s2[j], 16);
        s1[j] += __shfl_xor(s1[j], 32); s2[j] += __shfl_xor(s2[j], 32);
    }
    if (kq == 0) {
#pragma unroll
        for (int j = 0; j < 2; ++j) {
            wps1[wave][j * 16 + lr] = s1[j];
            wps2[wave][j * 16 + lr] = s2[j];
        }
    }
    __syncthreads();
    if (t < 32) {
        float a1 = wps1[0][t] + wps1[1][t] + wps1[2][t] + wps1[3][t];
        float a2 = wps2[0][t] + wps2[1][t] + wps2[2][t] + wps2[3][t];
        const float mean = a1 * (1.0f / 256.0f);
        const float var  = a2 * (1.0f / 256.0f) - mean * mean;   // biased (jnp.var)
        const float istd = rsqrtf(var + 1e-5f);
        const float ga = gamma[gcol0 + t];
        sa[t] = ga * istd;
        sb[t] = beta[gcol0 + t] - mean * ga * istd;
    }
    __syncthreads();

    // apply affine + swish; C/D layout col=lane&15, row=(lane>>4)*4+reg
#pragma unroll
    for (int i = 0; i < 4; ++i) {
        const int row0 = wave * 64 + i * 16 + kq * 4;
#pragma unroll
        for (int j = 0; j < 2; ++j) {
            const int col = j * 16 + lr;
            const float a = sa[col], b2 = sb[col];
#pragma unroll
            for (int r = 0; r < 4; ++r) {
                const float z = a * acc[i][j][r] + b2;
                out[(size_t)(row0 + r) * 8192 + gcol0 + col] = z / (1.0f + expf(-z));
            }
        }
    }
}

extern "C" void kernel_launch(void* const* d_in, const int* in_sizes, int n_in,
                              void* d_out, int out_size, void* d_ws, size_t ws_size,
                              hipStream_t stream) {
    const float* x     = (const float*)d_in[0];
    const float* W     = (const float*)d_in[1];
    // d_in[2] = bias: cancelled exactly by BN mean subtraction -> unused
    const float* gamma = (const float*)d_in[3];
    const float* beta  = (const float*)d_in[4];
    // d_in[5] = mask: implicit in block structure -> unused
    float* out = (float*)d_out;

    fused_kernel<<<256, 256, 0, stream>>>(x, W, gamma, beta, out);
}

// Round 15
// 23.333 us; speedup vs baseline: 1.3702x; 1.3702x over previous
//
#include <hip/hip_runtime.h>
#include <hip/hip_bf16.h>

// DecoderBlock: block-sparse masked linear (8 GEMMs M=256,N=1024,K=1024)
// + BatchNorm1d (batch stats; bias cancels exactly) + Swish.
// Round-15 = r10 (best, 25.6us) with 512 threads / 8 waves per block:
// 2 waves/SIMD so the LDS pipe, VALU(cvt) and MFMA pipe overlap WITHIN a
// step via wave co-scheduling (m114). Same tile (256x32), same LDS layout
// and swizzles, same W-ring(4) issued 3 ahead, same counted-vmcnt proof.
// grid 256 = 8 g x 32 nt; g=bid&7 -> XCD-local x slice; 1 block/CU (112KB).

typedef float  f32x4  __attribute__((ext_vector_type(4)));
typedef short  short8 __attribute__((ext_vector_type(8)));
typedef unsigned short u16x8 __attribute__((ext_vector_type(8)));
typedef unsigned int   u32x2 __attribute__((ext_vector_type(2)));

static __device__ __forceinline__ unsigned int f2bf(float f) {
    unsigned int u = __float_as_uint(f);
    u += 0x7FFFu + ((u >> 16) & 1u);          // RNE (inputs finite)
    return u >> 16;
}

#define GLL(gp, lp) __builtin_amdgcn_global_load_lds( \
    (const __attribute__((address_space(1))) unsigned int*)(gp), \
    (__attribute__((address_space(3))) unsigned int*)(lp), 16, 0, 0)

// ---------------- x f32 -> bf16 (12 MB traffic; result L2/L3-resident) ----------------
__global__ __launch_bounds__(256) void conv_kernel(const float* __restrict__ x,
                                                   unsigned short* __restrict__ xb) {
    const int base = blockIdx.x * 1024 + threadIdx.x;
#pragma unroll
    for (int i = 0; i < 4; ++i) {
        const int cid = base + i * 256;               // 8-float chunk id
        const f32x4 a = *(const f32x4*)(x + (size_t)cid * 8);
        const f32x4 b = *(const f32x4*)(x + (size_t)cid * 8 + 4);
        u16x8 v;
        v[0] = f2bf(a[0]); v[1] = f2bf(a[1]); v[2] = f2bf(a[2]); v[3] = f2bf(a[3]);
        v[4] = f2bf(b[0]); v[5] = f2bf(b[1]); v[6] = f2bf(b[2]); v[7] = f2bf(b[3]);
        *(u16x8*)(xb + (size_t)cid * 8) = v;
    }
}

// ---------------- fused GEMM + BN + Swish, 8 waves ----------------
// Block: M=256 x N=32, K=1024, BK=64 (16 steps). 8 waves x 32 rows each.
// A: [256][64] bf16 LDS x3 (GLL, src pre-swizzle c^=r&7), issued 2 ahead
//    (4 GLL/thread). W: f32 reg-ring depth 4 (1 f32x4/thread), issued 3 ahead.
// vmcnt (in-order, per wave): iter st issues A(st+2)4 then W(st+3)1;
// WRITEB(st+1) retires thru W(st+1) (older than A(st+1)); outstanding then =
// A(st+1)4 + W(st+2)1 + A(st+2)4 + W(st+3)1 = 10 -> vmcnt(6) retires A(st+1).
// Tail: st=13 -> vmcnt(5); st=14 -> vmcnt(0).
__global__ __launch_bounds__(512, 1) void fused_kernel(
    const unsigned short* __restrict__ xb, const float* __restrict__ W,
    const float* __restrict__ gamma, const float* __restrict__ beta,
    float* __restrict__ out)
{
    __shared__ __align__(16) char ldsA[3][32768];
    __shared__ __align__(16) char ldsB[2][4096];
    __shared__ float wps1[8][32], wps2[8][32];
    __shared__ float sa[32], sb[32];

    const int bid = blockIdx.x;
    const int g   = bid & 7;               // channel group -> XCD (round-robin)
    const int nt  = bid >> 3;              // 0..31
    const int o   = g * 4 + (nt >> 3);
    const int f0  = (nt & 7) * 32;
    const int gcol0 = o * 256 + f0;

    const int t    = threadIdx.x;          // 0..511
    const int wave = t >> 6;               // 0..7, rows wave*32..wave*32+31
    const int lane = t & 63;
    const int lr   = lane & 15;
    const int kq   = lane >> 4;

    f32x4 acc[2][2];
    const f32x4 zero = {0.f, 0.f, 0.f, 0.f};
#pragma unroll
    for (int i = 0; i < 2; ++i) { acc[i][0] = zero; acc[i][1] = zero; }

    f32x4 breg[4];                         // W ring depth 4, 1 f32x4/thread

    auto ISSUE_A = [&](int st) {           // 4 GLL (16B), source pre-swizzled
        const unsigned short* asrc = xb + g * 1024 + st * 64;
        char* Ab = ldsA[st % 3];
#pragma unroll
        for (int i = 0; i < 4; ++i) {
            const int cid = i * 512 + t;            // 0..2047
            const int r = cid >> 3, c = cid & 7;    // row 0..255, chunk 0..7
            GLL(asrc + (size_t)r * 8192 + (c ^ (r & 7)) * 8, Ab + cid * 16);
        }
    };
    auto ISSUE_W = [&](int st) {           // 1 x 16B into ring slot st&3
        const int cp = st >> 2, kc = (st & 3) * 64;
        const float* bsrc = W + ((size_t)((o * 32 + g * 4 + cp) * 256 + f0)) * 256 + kc;
        breg[st & 3] = *(const f32x4*)(bsrc + (size_t)(t >> 4) * 256 + (t & 15) * 4);
    };
    auto WRITEB = [&](int st) {            // cvt + swizzled ds_write_b64 (3-iter W lead)
        const int n = t >> 4;              // feature row 0..31
        const int ch = (t & 15) >> 1;      // 16B chunk 0..7
        const int half = t & 1;
        const f32x4 v = breg[st & 3];
        u32x2 d;
        d[0] = f2bf(v[0]) | (f2bf(v[1]) << 16);
        d[1] = f2bf(v[2]) | (f2bf(v[3]) << 16);
        *(u32x2*)(ldsB[st & 1] + n * 128 + ((ch ^ (n & 7)) * 16) + half * 8) = d;
    };
    auto COMPUTE = [&](int st) {
        const char* Ab = ldsA[st % 3];
        const char* Bb = ldsB[st & 1];
#pragma unroll
        for (int ks = 0; ks < 2; ++ks) {
            short8 af[2], bfr[2];
#pragma unroll
            for (int i = 0; i < 2; ++i) {
                const int ra = wave * 32 + i * 16 + lr;
                af[i] = *(const short8*)(Ab + ra * 128 + (((ks * 4 + kq) ^ (ra & 7)) * 16));
            }
#pragma unroll
            for (int j = 0; j < 2; ++j) {
                const int n = j * 16 + lr;
                bfr[j] = *(const short8*)(Bb + n * 128 + (((ks * 4 + kq) ^ (n & 7)) * 16));
            }
#pragma unroll
            for (int i = 0; i < 2; ++i)
#pragma unroll
                for (int j = 0; j < 2; ++j)
                    acc[i][j] = __builtin_amdgcn_mfma_f32_16x16x32_bf16(af[i], bfr[j], acc[i][j], 0, 0, 0);
        }
    };

    // prologue: A(0),A(1) then W(0..2); WRITEB(0) waits W(0) -> retires A(0),A(1).
    ISSUE_A(0);
    ISSUE_A(1);
    ISSUE_W(0);
    ISSUE_W(1);
    ISSUE_W(2);
    WRITEB(0);
    asm volatile("s_waitcnt lgkmcnt(0)" ::: "memory");
    __builtin_amdgcn_s_barrier();

#pragma unroll
    for (int st = 0; st < 16; ++st) {
        COMPUTE(st);                                   // reads A[st%3], B[st&1]
        if (st <= 13) ISSUE_A(st + 2);                 // A ring: 3-deep, disjoint
        if (st <= 12) ISSUE_W(st + 3);                 // newest vm ops: W
        if (st <= 14) {
            WRITEB(st + 1);                            // waits W(st+1) only
            if (st <= 12) {
                asm volatile("s_waitcnt vmcnt(6)" ::: "memory");   // retire A(st+1)
            } else if (st == 13) {
                asm volatile("s_waitcnt vmcnt(5)" ::: "memory");   // retire A(14)
            } else {
                asm volatile("s_waitcnt vmcnt(0)" ::: "memory");   // drain A(15)
            }
            asm volatile("s_waitcnt lgkmcnt(0)" ::: "memory");
            __builtin_amdgcn_s_barrier();
        }
    }

    // ---------------- fused BN + Swish epilogue ----------------
    float s1[2] = {0.f, 0.f}, s2[2] = {0.f, 0.f};
#pragma unroll
    for (int i = 0; i < 2; ++i)
#pragma unroll
        for (int j = 0; j < 2; ++j)
#pragma unroll
            for (int r = 0; r < 4; ++r) {
                const float v = acc[i][j][r];
                s1[j] += v; s2[j] += v * v;
            }
#pragma unroll
    for (int j = 0; j < 2; ++j) {          // reduce across kq groups (lanes sharing lr)
        s1[j] += __shfl_xor(s1[j], 16); s2[j] += __shfl_xor(s2[j], 16);
        s1[j] += __shfl_xor(s1[j], 32); s2[j] += __shfl_xor(s2[j], 32);
    }
    if (kq == 0) {
#pragma unroll
        for (int j = 0; j < 2; ++j) {
            wps1[wave][j * 16 + lr] = s1[j];
            wps2[wave][j * 16 + lr] = s2[j];
        }
    }
    __syncthreads();
    if (t < 32) {
        float a1 = 0.f, a2 = 0.f;
#pragma unroll
        for (int q = 0; q < 8; ++q) { a1 += wps1[q][t]; a2 += wps2[q][t]; }
        const float mean = a1 * (1.0f / 256.0f);
        const float var  = a2 * (1.0f / 256.0f) - mean * mean;   // biased (jnp.var)
        const float istd = rsqrtf(var + 1e-5f);
        const float ga = gamma[gcol0 + t];
        sa[t] = ga * istd;
        sb[t] = beta[gcol0 + t] - mean * ga * istd;
    }
    __syncthreads();

    // apply affine + swish; C/D layout col=lane&15, row=(lane>>4)*4+reg
#pragma unroll
    for (int i = 0; i < 2; ++i) {
        const int row0 = wave * 32 + i * 16 + kq * 4;
#pragma unroll
        for (int j = 0; j < 2; ++j) {
            const int col = j * 16 + lr;
            const float a = sa[col], b2 = sb[col];
#pragma unroll
            for (int r = 0; r < 4; ++r) {
                const float z = a * acc[i][j][r] + b2;
                out[(size_t)(row0 + r) * 8192 + gcol0 + col] = z / (1.0f + expf(-z));
            }
        }
    }
}

extern "C" void kernel_launch(void* const* d_in, const int* in_sizes, int n_in,
                              void* d_out, int out_size, void* d_ws, size_t ws_size,
                              hipStream_t stream) {
    const float* x     = (const float*)d_in[0];
    const float* W     = (const float*)d_in[1];
    // d_in[2] = bias: cancelled exactly by BN mean subtraction -> unused
    const float* gamma = (const float*)d_in[3];
    const float* beta  = (const float*)d_in[4];
    // d_in[5] = mask: implicit in block structure -> unused
    float* out = (float*)d_out;

    unsigned short* xb = (unsigned short*)d_ws;   // 4MB bf16 x

    conv_kernel<<<256, 256, 0, stream>>>(x, xb);
    fused_kernel<<<256, 512, 0, stream>>>(xb, W, gamma, beta, out);
}